// Round 7
// baseline (691.146 us; speedup 1.0000x reference)
//
#include <hip/hip_runtime.h>
#include <stdint.h>

#define T_SEQ 4096
#define HID   2048
#define NH    16
#define HD    128

typedef __attribute__((ext_vector_type(8))) short short8;
typedef __attribute__((ext_vector_type(4))) short short4v;
typedef __attribute__((ext_vector_type(4))) float f32x4;

typedef __attribute__((address_space(1))) void as1_void;
typedef __attribute__((address_space(3))) void as3_void;

__device__ __forceinline__ unsigned short f2bf(float f){
  unsigned u = __builtin_bit_cast(unsigned, f);
  u += 0x7fffu + ((u >> 16) & 1u);
  return (unsigned short)(u >> 16);
}
__device__ __forceinline__ float bf2f(unsigned short b){
  unsigned u = ((unsigned)b) << 16;
  return __builtin_bit_cast(float, u);
}
// async global->LDS, 16B per lane. LDS side is wave-uniform base + lane*16.
__device__ __forceinline__ void gll16(const void* g, void* l){
  __builtin_amdgcn_global_load_lds((as1_void*)(uintptr_t)g,
                                   (as3_void*)(unsigned)(uintptr_t)l, 16, 0, 0);
}

#define VM_WAIT8    asm volatile("s_waitcnt vmcnt(8)" ::: "memory")
__device__ __forceinline__ void barrier_fence(){
  asm volatile("" ::: "memory");
  __builtin_amdgcn_s_barrier();
  asm volatile("" ::: "memory");
}

// ---------------- fp32 -> bf16 conversion of X ----------------
__global__ __launch_bounds__(256) void conv_x_k(const float* __restrict__ X,
                                                unsigned short* __restrict__ O){
  int i = (blockIdx.x * 256 + threadIdx.x) * 4;
  float4 v = *(const float4*)(X + i);
  short4v o;
  o[0] = (short)f2bf(v.x); o[1] = (short)f2bf(v.y);
  o[2] = (short)f2bf(v.z); o[3] = (short)f2bf(v.w);
  *(short4v*)(O + i) = o;
}

// ------------- weight transpose + bf16: W[k][n] -> Wt[n][k] -------------
__global__ __launch_bounds__(256) void conv_wt_k(const float* __restrict__ W0,
                                                 const float* __restrict__ W1,
                                                 const float* __restrict__ W2,
                                                 const float* __restrict__ W3,
                                                 unsigned short* __restrict__ Wt){
  const float* W = (blockIdx.z == 0) ? W0 : (blockIdx.z == 1) ? W1
                   : (blockIdx.z == 2) ? W2 : W3;
  unsigned short* out = Wt + (size_t)blockIdx.z * HID * HID;
  __shared__ float tile[32][33];
  const int x = threadIdx.x;       // 0..31
  const int y = threadIdx.y;       // 0..7
  const int k0 = blockIdx.y * 32, n0 = blockIdx.x * 32;
#pragma unroll
  for (int i = 0; i < 4; ++i){
    int r = y * 4 + i;
    tile[r][x] = W[(size_t)(k0 + r) * HID + n0 + x];
  }
  __syncthreads();
#pragma unroll
  for (int i = 0; i < 4; ++i){
    int r = y * 4 + i;
    out[(size_t)(n0 + r) * HID + k0 + x] = f2bf(tile[x][r]);
  }
}

// ---------------- GEMM: C[M][N] = A[M][K=2048] * Bt[N][K]^T ----------------
// 128x128 tile, 4 waves (2x2), BK=64 (32 iters), global_load_lds(16B).
// LDS slot (row, c) holds global chunk c ^ (row&7); fragment read chunk
// (ks*4+qd) ^ (mm&7) -> bank-uniform.
// MODE 0: Q/K blocks scatter bf16 [h][t][d]; V blocks (bn>=4096) transpose
//   the 128x128 tile through LDS (chunk-XOR swizzle) and store Vt [h][d][t]
//   as 256B-contiguous runs.
// MODE 1: epilogue writes fp32 C row-major [M][NTOT].
template<int MODE, int NTOT>
__global__ __launch_bounds__(256, 3) void gemm_bt(
    const unsigned short* __restrict__ A,
    const unsigned short* __restrict__ Bt,
    unsigned short* __restrict__ Qb,
    unsigned short* __restrict__ Kb,
    unsigned short* __restrict__ Vt,
    float* __restrict__ Cf)
{
  constexpr int K = HID;
  __shared__ __align__(16) unsigned short lAB[16384];   // lA | lB ; reused as lT
  unsigned short* lA = lAB;
  unsigned short* lB = lAB + 8192;

  const int tid  = threadIdx.x;
  const int wave = tid >> 6;
  const int lane = tid & 63;
  const int qd   = lane >> 4;
  const int mm   = lane & 15;
  const int m7   = mm & 7;
  const int wm   = wave >> 1;
  const int wn   = wave & 1;
  const int bm   = blockIdx.y * 128;
  const int bn   = blockIdx.x * 128;

  const unsigned short* ga[4];
  const unsigned short* gb[4];
  unsigned short* la[4];
  unsigned short* lbp[4];
#pragma unroll
  for (int i = 0; i < 4; ++i){
    int s0   = (wave * 4 + i) * 64;   // wave-uniform base slot
    int slot = s0 + lane;
    int row  = slot >> 3;
    int kb   = (slot & 7) ^ (row & 7);
    ga[i]  = A  + (size_t)(bm + row) * K + kb * 8;
    gb[i]  = Bt + (size_t)(bn + row) * K + kb * 8;
    la[i]  = lA + s0 * 8;
    lbp[i] = lB + s0 * 8;
  }

  int abase[4], bbase[4];
#pragma unroll
  for (int t = 0; t < 4; ++t){
    abase[t] = (wm * 64 + t * 16 + mm) * 8;
    bbase[t] = (wn * 64 + t * 16 + mm) * 8;
  }

  const f32x4 fzero = {0.f, 0.f, 0.f, 0.f};
  f32x4 acc[4][4];
#pragma unroll
  for (int i = 0; i < 4; ++i)
#pragma unroll
    for (int j = 0; j < 4; ++j) acc[i][j] = fzero;

  for (int k0 = 0; k0 < K; k0 += 64){
    __syncthreads();
#pragma unroll
    for (int i = 0; i < 4; ++i){
      gll16(ga[i] + k0, la[i]);
      gll16(gb[i] + k0, lbp[i]);
    }
    __syncthreads();
#pragma unroll
    for (int ks = 0; ks < 2; ++ks){
      const int co = (ks * 4 + qd) ^ m7;
      short8 af[4], bfv[4];
#pragma unroll
      for (int t = 0; t < 4; ++t) af[t]  = *(const short8*)(lA + (abase[t] + co) * 8);
#pragma unroll
      for (int t = 0; t < 4; ++t) bfv[t] = *(const short8*)(lB + (bbase[t] + co) * 8);
#pragma unroll
      for (int i = 0; i < 4; ++i)
#pragma unroll
        for (int j = 0; j < 4; ++j)
          acc[i][j] = __builtin_amdgcn_mfma_f32_16x16x32_bf16(af[i], bfv[j], acc[i][j], 0, 0, 0);
    }
  }

  if (MODE == 0 && bn >= 4096){
    // ---- V block: 128x128 tile transpose via LDS, coalesced Vt stores ----
    __syncthreads();   // all lA/lB fragment reads done before overwrite
    unsigned short* lT = lAB;   // [d=128][t-chunks 32][4] u16, chunk XOR swz
#pragma unroll
    for (int i = 0; i < 4; ++i){
#pragma unroll
      for (int j = 0; j < 4; ++j){
        const int d_l   = wn * 64 + j * 16 + mm;
        const int chunk = wm * 16 + i * 4 + qd;     // t_local>>2
        const int ch    = chunk ^ (d_l & 31);
        short4v pk;
#pragma unroll
        for (int r = 0; r < 4; ++r) pk[r] = (short)f2bf(acc[i][j][r]);
        *(short4v*)(lT + d_l * 128 + ch * 4) = pk;
      }
    }
    __syncthreads();
    const int hV = (bn >> 7) - 32;
    const int dd = tid >> 4;          // 0..15
    const int tg = tid & 15;          // 8-t group -> 16B store
#pragma unroll
    for (int p = 0; p < 8; ++p){
      const int d_l = p * 16 + dd;
      const int c0  = (tg * 2)     ^ (d_l & 31);
      const int c1  = (tg * 2 + 1) ^ (d_l & 31);
      short4v lo = *(const short4v*)(lT + d_l * 128 + c0 * 4);
      short4v hi = *(const short4v*)(lT + d_l * 128 + c1 * 4);
      short8 ov;
      ov[0] = lo[0]; ov[1] = lo[1]; ov[2] = lo[2]; ov[3] = lo[3];
      ov[4] = hi[0]; ov[5] = hi[1]; ov[6] = hi[2]; ov[7] = hi[3];
      *(short8*)(Vt + ((size_t)(hV * HD + d_l)) * T_SEQ + bm + tg * 8) = ov;
    }
    return;
  }

#pragma unroll
  for (int i = 0; i < 4; ++i){
#pragma unroll
    for (int j = 0; j < 4; ++j){
      const int col = bn + wn * 64 + j * 16 + mm;
#pragma unroll
      for (int r = 0; r < 4; ++r){
        const int row = bm + wm * 64 + i * 16 + qd * 4 + r;
        const float v = acc[i][j][r];
        if (MODE == 0){
          const int nn  = col & 2047;
          const int h   = nn >> 7;
          const int d   = nn & 127;
          const unsigned short bv = f2bf(v);
          if (col < 2048)      Qb[((size_t)h * T_SEQ + row) * HD + d] = bv;
          else                 Kb[((size_t)h * T_SEQ + row) * HD + d] = bv;
        } else {
          Cf[(size_t)row * NTOT + col] = v;
        }
      }
    }
  }
}

// ---------------- RoPE on Q and K (in place, bf16) ----------------
__global__ __launch_bounds__(256) void rope_k(unsigned short* __restrict__ Qb,
                                              unsigned short* __restrict__ Kb){
  const int j = threadIdx.x & 63;
  const int t = blockIdx.x * 4 + (threadIdx.x >> 6);
  const int h = blockIdx.y;
  const float fr = (float)t * __expf(-(float)j * (9.210340371976184f / 64.f));
  const float cs = cosf(fr), sn = sinf(fr);
  const size_t base = ((size_t)h * T_SEQ + t) * HD;
  {
    float x1 = bf2f(Qb[base + j]), x2 = bf2f(Qb[base + j + 64]);
    Qb[base + j]      = f2bf(x1 * cs - x2 * sn);
    Qb[base + j + 64] = f2bf(x2 * cs + x1 * sn);
  }
  {
    float x1 = bf2f(Kb[base + j]), x2 = bf2f(Kb[base + j + 64]);
    Kb[base + j]      = f2bf(x1 * cs - x2 * sn);
    Kb[base + j + 64] = f2bf(x2 * cs + x1 * sn);
  }
}

// ---------------- flash attention v9 (LDS off the critical pipe) ----------------
// R1-R3 counters: dur ~133us invariant across {VALU diet, occupancy 2->3},
// MfmaUtil ~23, VALUBusy ~40, bank-conflict constant 9.7M. Ledger: LDS pipe
// demand ~870 cy/block-iter x3 blocks > the 2474-cy window -> LDS-BOUND.
// v9 cuts LDS traffic ~2.5x:
//  - V fragments read DIRECTLY from global (Vt [h][d][t] makes the B-frag a
//    contiguous 16B/lane read; K+V head-pinned to XCD -> L2-resident),
//    prefetched one full iteration ahead into registers (T14). Removes V
//    staging writes AND V LDS reads.
//  - K double-buffered in LDS, ONE barrier/iter: prefetch K(it+1)->buf^1
//    right after entry barrier (all waves past B(it) => done reading buf^1);
//    VM_WAIT(8) at iter end retires K(it+1) while vf(it+1)'s 8 loads fly.
//  - Loop 2x-unrolled so vf banks + K-buffer offsets are compile-time.
// lP stays LDS but is wave-private (no barrier needed for it).
__global__ __launch_bounds__(256, 3) void attn_k(
    const unsigned short* __restrict__ Qb,   // [NH][T][HD]
    const unsigned short* __restrict__ Kb,   // [NH][T][HD]
    const unsigned short* __restrict__ Vt,   // [NH][HD][T]
    unsigned short* __restrict__ Yb)         // [T][HID]
{
  __shared__ __align__(16) unsigned char smem[41216];
  unsigned short* lK = (unsigned short*)smem;              // 2 x [64 keys][128 d] 32 KB
  unsigned short (*lP)[32][32] = (unsigned short(*)[32][32])(smem + 32768); // 8 KB
  float* lL = (float*)(smem + 40960);                      // [64]
  float* lO = (float*)smem;                                // [128 d][68] epilogue overlay

  const int tid  = threadIdx.x;
  const int w    = tid >> 6;
  const int rg   = w >> 1;
  const int kg   = w & 1;
  const int lane = tid & 63;
  const int qd   = lane >> 4;
  const int cc   = lane & 15;
  const int cx   = cc & 7;

  const int b  = blockIdx.x;            // 1024 blocks
  const int h  = b & 15;                // head; h&7 = b&7 -> XCD pinned
  const int tp = 63 - (b >> 4);         // big tiles dispatched first
  const int qrow0 = tp * 64 + rg * 32;
  const int iters = tp + 1;

  // K staging source addressing (swizzle on fetch side; slot chunk c holds
  // global chunk c ^ (row&7))
  const int ce  = cc ^ qd;
  const int dlt = (ce & 4) ? -32 : 32;
  const unsigned short* gKbp = Kb + ((size_t)h * T_SEQ + w * 16 + qd) * HD + ce * 8;

  // V direct-from-global B-fragment base: lane (qd,cc) reads
  // Vt[h][dn*16+cc][k0 + kg*32 + qd*8 .. +7] (16B contiguous)
  const unsigned short* gVf = Vt + ((size_t)h * HD + cc) * T_SEQ + kg * 32 + qd * 8;

  // lP store columns (swizzled chunk); read chunk = qd ^ (cc>>2)
  const int pc0 = (((cc >> 3)    ) ^ qd) * 8 + (cc & 7);   // nt=0
  const int pc1 = (((cc >> 3) + 2) ^ qd) * 8 + (cc & 7);   // nt=1

  const f32x4 fzero = {0.f, 0.f, 0.f, 0.f};
  // 50*tanh(s*SCALE/50)*log2(e) ~= s*(B0 + B1*s^2 + B2*s^4)
  const float B0 = 0.09016844006f;
  const float B1 = -4.6962728e-8f;
  const float B2 = 2.9351706e-14f;
  const float CLP = 72.134752f;        // 50 * log2(e)
  short8 onesv;
#pragma unroll
  for (int j = 0; j < 8; ++j) onesv[j] = (short)0x3F80;    // bf16 1.0

  // prologue: stage K(0) -> buf0 (4 gll16), load vfA = V(0) (8 dwordx4)
  short8 vfA[8], vfB[8];
  {
    unsigned short* dK = lK + w * 2048;
#pragma unroll
    for (int i = 0; i < 4; ++i)
      gll16(gKbp + (size_t)(i * 4) * HD + ((i & 1) ? dlt : 0), dK + i * 512);
#pragma unroll
    for (int dn = 0; dn < 8; ++dn)
      vfA[dn] = *(const short8*)(gVf + (size_t)(dn * 16) * T_SEQ);
  }

  // Q fragments: A-layout, rows qrow0 + mt*16 + cc, d = ks*32 + qd*8
  short8 qf[2][4];
#pragma unroll
  for (int mt = 0; mt < 2; ++mt)
#pragma unroll
    for (int ks = 0; ks < 4; ++ks)
      qf[mt][ks] = *(const short8*)(Qb + ((size_t)h * T_SEQ + qrow0 + mt * 16 + cc) * HD + ks * 32 + qd * 8);

  f32x4 o[2][8];
  f32x4 acc_l[2];
#pragma unroll
  for (int mt = 0; mt < 2; ++mt){
#pragma unroll
    for (int dn = 0; dn < 8; ++dn) o[mt][dn] = fzero;
    acc_l[mt] = fzero;
  }

  VM_WAIT8;   // retire K(0) (vfA's 8 loads newer, stay in flight)

#define ATTN_BODY(VFC, VFN, RDOFF, WROFF)                                      \
  {                                                                            \
    barrier_fence();   /* all waves' K(it) landed; buf(RDOFF) valid */         \
    const int k0 = it * 64;                                                    \
    if (it + 1 < iters){                                                       \
      const unsigned short* gK = gKbp + (size_t)(k0 + 64) * HD;                \
      unsigned short* dK = lK + (WROFF) + w * 2048;                            \
      _Pragma("unroll")                                                        \
      for (int i = 0; i < 4; ++i)                                              \
        gll16(gK + (size_t)(i * 4) * HD + ((i & 1) ? dlt : 0), dK + i * 512);  \
      _Pragma("unroll")                                                        \
      for (int dn = 0; dn < 8; ++dn)                                           \
        VFN[dn] = *(const short8*)(gVf + (size_t)(dn * 16) * T_SEQ + k0 + 64); \
    }                                                                          \
    /* S = Q K^T : wave's keys = k0 + kg*32 + nt*16 + cc */                    \
    f32x4 S[2][2];                                                             \
    _Pragma("unroll")                                                          \
    for (int mt = 0; mt < 2; ++mt)                                             \
      _Pragma("unroll")                                                        \
      for (int nt = 0; nt < 2; ++nt) S[mt][nt] = fzero;                        \
    __builtin_amdgcn_s_setprio(1);                                             \
    _Pragma("unroll")                                                          \
    for (int nt = 0; nt < 2; ++nt){                                            \
      short8 kf[4];                                                            \
      _Pragma("unroll")                                                        \
      for (int ks = 0; ks < 4; ++ks)                                           \
        kf[ks] = *(const short8*)(lK + (RDOFF) +                               \
                   ((kg * 32 + nt * 16 + cc) * 16 + ((ks * 4 + qd) ^ cx)) * 8);\
      _Pragma("unroll")                                                        \
      for (int mt = 0; mt < 2; ++mt)                                           \
        _Pragma("unroll")                                                      \
        for (int ks = 0; ks < 4; ++ks)                                         \
          S[mt][nt] = __builtin_amdgcn_mfma_f32_16x16x32_bf16(qf[mt][ks],      \
                        kf[ks], S[mt][nt], 0, 0, 0);                           \
    }                                                                          \
    __builtin_amdgcn_s_setprio(0);                                             \
    const bool domask = (it == iters - 1);                                     \
    _Pragma("unroll")                                                          \
    for (int mt = 0; mt < 2; ++mt)                                             \
      _Pragma("unroll")                                                        \
      for (int nt = 0; nt < 2; ++nt)                                           \
        _Pragma("unroll")                                                      \
        for (int r = 0; r < 4; ++r){                                           \
          float s = S[mt][nt][r];                                              \
          float w2 = s * s;                                                    \
          float t = fmaf(w2, B2, B1);                                          \
          t = fmaf(w2, t, B0);                                                 \
          float a = s * t;                                                     \
          a = __builtin_amdgcn_fmed3f(a, -CLP, CLP);                           \
          float p = __builtin_amdgcn_exp2f(a);                                 \
          if (domask){                                                         \
            int col = k0 + kg * 32 + nt * 16 + cc;                             \
            int row = qrow0 + mt * 16 + qd * 4 + r;                            \
            if (col > row) p = 0.f;                                            \
          }                                                                    \
          unsigned u = __builtin_bit_cast(unsigned, p);                        \
          lP[w][mt * 16 + qd * 4 + r][nt ? pc1 : pc0] = (unsigned short)(u >> 16); \
        }                                                                      \
    /* P frags (wave-private RAW; compiler inserts the lgkm wait) */           \
    short8 pf[2];                                                              \
    _Pragma("unroll")                                                          \
    for (int mt = 0; mt < 2; ++mt)                                             \
      pf[mt] = *(const short8*)(&lP[w][mt * 16 + cc][(qd ^ (cc >> 2)) * 8]);   \
    /* O += P V (vf from registers) ; l += P . 1 */                            \
    __builtin_amdgcn_s_setprio(1);                                             \
    _Pragma("unroll")                                                          \
    for (int dn = 0; dn < 8; ++dn)                                             \
      _Pragma("unroll")                                                        \
      for (int mt = 0; mt < 2; ++mt)                                           \
        o[mt][dn] = __builtin_amdgcn_mfma_f32_16x16x32_bf16(pf[mt], VFC[dn],   \
                      o[mt][dn], 0, 0, 0);                                     \
    _Pragma("unroll")                                                          \
    for (int mt = 0; mt < 2; ++mt)                                             \
      acc_l[mt] = __builtin_amdgcn_mfma_f32_16x16x32_bf16(pf[mt], onesv,       \
                    acc_l[mt], 0, 0, 0);                                       \
    __builtin_amdgcn_s_setprio(0);                                             \
    VM_WAIT8;   /* retire K(it+1) (4 oldest); vf(it+1) stays in flight */      \
  }

  {
    int it = 0;
    while (true){
      ATTN_BODY(vfA, vfB, 0, 8192);      // even it: read buf0, write buf1
      if (++it == iters) break;
      ATTN_BODY(vfB, vfA, 8192, 0);      // odd it: read buf1, write buf0
      if (++it == iters) break;
    }
  }
#undef ATTN_BODY

  // ---- epilogue: merge kg partials (additive), normalize, store ----
  // acc_l[mt][r] = row-sum for q-row mt*16+qd*4+r (same value in all cc)
  __syncthreads();   // full drain; all lK reads done before lO overlays
  if (kg == 1){
#pragma unroll
    for (int mt = 0; mt < 2; ++mt){
#pragma unroll
      for (int dn = 0; dn < 8; ++dn)
        *(f32x4*)&lO[(dn * 16 + cc) * 68 + rg * 32 + mt * 16 + qd * 4] = o[mt][dn];
      if (cc == 0){
#pragma unroll
        for (int r = 0; r < 4; ++r)
          lL[rg * 32 + mt * 16 + qd * 4 + r] = acc_l[mt][r];
      }
    }
  }
  __syncthreads();
  if (kg == 0){
#pragma unroll
    for (int mt = 0; mt < 2; ++mt){
      float inv[4];
#pragma unroll
      for (int r = 0; r < 4; ++r){
        float lt = acc_l[mt][r] + lL[rg * 32 + mt * 16 + qd * 4 + r];
        inv[r] = __builtin_amdgcn_rcpf(lt);
      }
#pragma unroll
      for (int dn = 0; dn < 8; ++dn){
        f32x4 oo = o[mt][dn] + *(const f32x4*)&lO[(dn * 16 + cc) * 68 + rg * 32 + mt * 16 + qd * 4];
#pragma unroll
        for (int r = 0; r < 4; ++r){
          int row = qrow0 + mt * 16 + qd * 4 + r;
          Yb[(size_t)row * HID + h * HD + dn * 16 + cc] = f2bf(oo[r] * inv[r]);
        }
      }
    }
  }
}

extern "C" void kernel_launch(void* const* d_in, const int* in_sizes, int n_in,
                              void* d_out, int out_size, void* d_ws, size_t ws_size,
                              hipStream_t stream) {
  const float* X  = (const float*)d_in[0];
  const float* Wq = (const float*)d_in[1];
  const float* Wk = (const float*)d_in[2];
  const float* Wv = (const float*)d_in[3];
  const float* Wo = (const float*)d_in[4];
  float* out = (float*)d_out;

  unsigned short* ws = (unsigned short*)d_ws;
  unsigned short* Xb = ws;                                   // [T][HID]        16 MiB
  unsigned short* Wt = ws + (size_t)8  * 1024 * 1024;        // [4*2048][2048]  32 MiB
  unsigned short* Qb = ws + (size_t)24 * 1024 * 1024;        // [NH][T][HD]     16 MiB
  unsigned short* Kb = ws + (size_t)32 * 1024 * 1024;        // [NH][T][HD]     16 MiB
  unsigned short* Vt = ws + (size_t)40 * 1024 * 1024;        // [NH][HD][T]     16 MiB
  unsigned short* Yb = Xb;                                   // reuse X region

  conv_x_k<<<8192, 256, 0, stream>>>(X, Xb);
  conv_wt_k<<<dim3(64, 64, 4), dim3(32, 8), 0, stream>>>(Wq, Wk, Wv, Wo, Wt);
  gemm_bt<0, 6144><<<dim3(48, 32), 256, 0, stream>>>(Xb, Wt, Qb, Kb, Vt, nullptr);
  rope_k<<<dim3(1024, NH), 256, 0, stream>>>(Qb, Kb);
  attn_k<<<dim3(1024), 256, 0, stream>>>(Qb, Kb, Vt, Yb);
  gemm_bt<1, 2048><<<dim3(16, 32), 256, 0, stream>>>(Yb, Wt + (size_t)6144 * 2048,
                                                     nullptr, nullptr, nullptr, out);
}

// Round 9
// 441.644 us; speedup vs baseline: 1.5649x; 1.5649x over previous
//
#include <hip/hip_runtime.h>
#include <stdint.h>

#define T_SEQ 4096
#define HID   2048
#define NH    16
#define HD    128

typedef __attribute__((ext_vector_type(8))) short short8;
typedef __attribute__((ext_vector_type(4))) short short4v;
typedef __attribute__((ext_vector_type(4))) float f32x4;

typedef __attribute__((address_space(1))) void as1_void;
typedef __attribute__((address_space(3))) void as3_void;

__device__ __forceinline__ unsigned short f2bf(float f){
  unsigned u = __builtin_bit_cast(unsigned, f);
  u += 0x7fffu + ((u >> 16) & 1u);
  return (unsigned short)(u >> 16);
}
__device__ __forceinline__ float bf2f(unsigned short b){
  unsigned u = ((unsigned)b) << 16;
  return __builtin_bit_cast(float, u);
}
// async global->LDS, 16B per lane. LDS side is wave-uniform base + lane*16.
__device__ __forceinline__ void gll16(const void* g, void* l){
  __builtin_amdgcn_global_load_lds((as1_void*)(uintptr_t)g,
                                   (as3_void*)(unsigned)(uintptr_t)l, 16, 0, 0);
}

#define VM_WAIT0    asm volatile("s_waitcnt vmcnt(0)" ::: "memory")
#define LGKM_WAIT0  asm volatile("s_waitcnt lgkmcnt(0)" ::: "memory")
__device__ __forceinline__ void barrier_fence(){
  asm volatile("" ::: "memory");
  __builtin_amdgcn_s_barrier();
  asm volatile("" ::: "memory");
}

// ---------------- fp32 -> bf16 conversion of X ----------------
__global__ __launch_bounds__(256) void conv_x_k(const float* __restrict__ X,
                                                unsigned short* __restrict__ O){
  int i = (blockIdx.x * 256 + threadIdx.x) * 4;
  float4 v = *(const float4*)(X + i);
  short4v o;
  o[0] = (short)f2bf(v.x); o[1] = (short)f2bf(v.y);
  o[2] = (short)f2bf(v.z); o[3] = (short)f2bf(v.w);
  *(short4v*)(O + i) = o;
}

// ------------- weight transpose + bf16: W[k][n] -> Wt[n][k] -------------
__global__ __launch_bounds__(256) void conv_wt_k(const float* __restrict__ W0,
                                                 const float* __restrict__ W1,
                                                 const float* __restrict__ W2,
                                                 const float* __restrict__ W3,
                                                 unsigned short* __restrict__ Wt){
  const float* W = (blockIdx.z == 0) ? W0 : (blockIdx.z == 1) ? W1
                   : (blockIdx.z == 2) ? W2 : W3;
  unsigned short* out = Wt + (size_t)blockIdx.z * HID * HID;
  __shared__ float tile[32][33];
  const int x = threadIdx.x;       // 0..31
  const int y = threadIdx.y;       // 0..7
  const int k0 = blockIdx.y * 32, n0 = blockIdx.x * 32;
#pragma unroll
  for (int i = 0; i < 4; ++i){
    int r = y * 4 + i;
    tile[r][x] = W[(size_t)(k0 + r) * HID + n0 + x];
  }
  __syncthreads();
#pragma unroll
  for (int i = 0; i < 4; ++i){
    int r = y * 4 + i;
    out[(size_t)(n0 + r) * HID + k0 + x] = f2bf(tile[x][r]);
  }
}

// ---------------- GEMM: C[M][N] = A[M][K=2048] * Bt[N][K]^T ----------------
// 128x128 tile, 4 waves (2x2), BK=64 (32 iters), global_load_lds(16B).
// LDS slot (row, c) holds global chunk c ^ (row&7); fragment read chunk
// (ks*4+qd) ^ (mm&7) -> bank-uniform.
// R7: bijective XCD-chunked block swizzle (T1). Linear dispatch round-robins
// XCDs, so the 8 consecutive blocks sharing one A-panel land on 8 different
// L2s. Chunked remap gives XCD x the contiguous tile range [x*cpx,(x+1)*cpx)
// (= 4 full by-rows) -> A-panel re-reads become XCD-L2-local.
// Requires nwg % 8 == 0 (1536 and 512: both ok).
// MODE 0: Q/K blocks scatter bf16 [h][t][d]; V blocks (bn>=4096) transpose
//   the 128x128 tile through LDS (chunk-XOR swizzle) and store Vt [h][d][t]
//   as 256B-contiguous runs.
// MODE 1: epilogue writes fp32 C row-major [M][NTOT].
template<int MODE, int NTOT>
__global__ __launch_bounds__(256, 3) void gemm_bt(
    const unsigned short* __restrict__ A,
    const unsigned short* __restrict__ Bt,
    unsigned short* __restrict__ Qb,
    unsigned short* __restrict__ Kb,
    unsigned short* __restrict__ Vt,
    float* __restrict__ Cf)
{
  constexpr int K = HID;
  __shared__ __align__(16) unsigned short lAB[16384];   // lA | lB ; reused as lT
  unsigned short* lA = lAB;
  unsigned short* lB = lAB + 8192;

  const int tid  = threadIdx.x;
  const int wave = tid >> 6;
  const int lane = tid & 63;
  const int qd   = lane >> 4;
  const int mm   = lane & 15;
  const int m7   = mm & 7;
  const int wm   = wave >> 1;
  const int wn   = wave & 1;

  // XCD-chunked swizzle of the linear block id (x-fastest linearization)
  const int nbx = gridDim.x;
  const int id  = blockIdx.y * nbx + blockIdx.x;
  const int cpx = (nbx * gridDim.y) >> 3;        // blocks per XCD
  const int sid = (id & 7) * cpx + (id >> 3);
  const int bxs = sid % nbx;
  const int bys = sid / nbx;
  const int bm  = bys * 128;
  const int bn  = bxs * 128;

  const unsigned short* ga[4];
  const unsigned short* gb[4];
  unsigned short* la[4];
  unsigned short* lbp[4];
#pragma unroll
  for (int i = 0; i < 4; ++i){
    int s0   = (wave * 4 + i) * 64;   // wave-uniform base slot
    int slot = s0 + lane;
    int row  = slot >> 3;
    int kb   = (slot & 7) ^ (row & 7);
    ga[i]  = A  + (size_t)(bm + row) * K + kb * 8;
    gb[i]  = Bt + (size_t)(bn + row) * K + kb * 8;
    la[i]  = lA + s0 * 8;
    lbp[i] = lB + s0 * 8;
  }

  int abase[4], bbase[4];
#pragma unroll
  for (int t = 0; t < 4; ++t){
    abase[t] = (wm * 64 + t * 16 + mm) * 8;
    bbase[t] = (wn * 64 + t * 16 + mm) * 8;
  }

  const f32x4 fzero = {0.f, 0.f, 0.f, 0.f};
  f32x4 acc[4][4];
#pragma unroll
  for (int i = 0; i < 4; ++i)
#pragma unroll
    for (int j = 0; j < 4; ++j) acc[i][j] = fzero;

  for (int k0 = 0; k0 < K; k0 += 64){
    __syncthreads();
#pragma unroll
    for (int i = 0; i < 4; ++i){
      gll16(ga[i] + k0, la[i]);
      gll16(gb[i] + k0, lbp[i]);
    }
    __syncthreads();
#pragma unroll
    for (int ks = 0; ks < 2; ++ks){
      const int co = (ks * 4 + qd) ^ m7;
      short8 af[4], bfv[4];
#pragma unroll
      for (int t = 0; t < 4; ++t) af[t]  = *(const short8*)(lA + (abase[t] + co) * 8);
#pragma unroll
      for (int t = 0; t < 4; ++t) bfv[t] = *(const short8*)(lB + (bbase[t] + co) * 8);
#pragma unroll
      for (int i = 0; i < 4; ++i)
#pragma unroll
        for (int j = 0; j < 4; ++j)
          acc[i][j] = __builtin_amdgcn_mfma_f32_16x16x32_bf16(af[i], bfv[j], acc[i][j], 0, 0, 0);
    }
  }

  if (MODE == 0 && bn >= 4096){
    // ---- V block: 128x128 tile transpose via LDS, coalesced Vt stores ----
    __syncthreads();   // all lA/lB fragment reads done before overwrite
    unsigned short* lT = lAB;   // [d=128][t-chunks 32][4] u16, chunk XOR swz
#pragma unroll
    for (int i = 0; i < 4; ++i){
#pragma unroll
      for (int j = 0; j < 4; ++j){
        const int d_l   = wn * 64 + j * 16 + mm;
        const int chunk = wm * 16 + i * 4 + qd;     // t_local>>2
        const int ch    = chunk ^ (d_l & 31);
        short4v pk;
#pragma unroll
        for (int r = 0; r < 4; ++r) pk[r] = (short)f2bf(acc[i][j][r]);
        *(short4v*)(lT + d_l * 128 + ch * 4) = pk;
      }
    }
    __syncthreads();
    const int hV = (bn >> 7) - 32;
    const int dd = tid >> 4;          // 0..15
    const int tg = tid & 15;          // 8-t group -> 16B store
#pragma unroll
    for (int p = 0; p < 8; ++p){
      const int d_l = p * 16 + dd;
      const int c0  = (tg * 2)     ^ (d_l & 31);
      const int c1  = (tg * 2 + 1) ^ (d_l & 31);
      short4v lo = *(const short4v*)(lT + d_l * 128 + c0 * 4);
      short4v hi = *(const short4v*)(lT + d_l * 128 + c1 * 4);
      short8 ov;
      ov[0] = lo[0]; ov[1] = lo[1]; ov[2] = lo[2]; ov[3] = lo[3];
      ov[4] = hi[0]; ov[5] = hi[1]; ov[6] = hi[2]; ov[7] = hi[3];
      *(short8*)(Vt + ((size_t)(hV * HD + d_l)) * T_SEQ + bm + tg * 8) = ov;
    }
    return;
  }

#pragma unroll
  for (int i = 0; i < 4; ++i){
#pragma unroll
    for (int j = 0; j < 4; ++j){
      const int col = bn + wn * 64 + j * 16 + mm;
#pragma unroll
      for (int r = 0; r < 4; ++r){
        const int row = bm + wm * 64 + i * 16 + qd * 4 + r;
        const float v = acc[i][j][r];
        if (MODE == 0){
          const int nn  = col & 2047;
          const int h   = nn >> 7;
          const int d   = nn & 127;
          const unsigned short bv = f2bf(v);
          if (col < 2048)      Qb[((size_t)h * T_SEQ + row) * HD + d] = bv;
          else                 Kb[((size_t)h * T_SEQ + row) * HD + d] = bv;
        } else {
          Cf[(size_t)row * NTOT + col] = v;
        }
      }
    }
  }
}

// ---------------- RoPE on Q and K (in place, bf16) ----------------
__global__ __launch_bounds__(256) void rope_k(unsigned short* __restrict__ Qb,
                                              unsigned short* __restrict__ Kb){
  const int j = threadIdx.x & 63;
  const int t = blockIdx.x * 4 + (threadIdx.x >> 6);
  const int h = blockIdx.y;
  const float fr = (float)t * __expf(-(float)j * (9.210340371976184f / 64.f));
  const float cs = cosf(fr), sn = sinf(fr);
  const size_t base = ((size_t)h * T_SEQ + t) * HD;
  {
    float x1 = bf2f(Qb[base + j]), x2 = bf2f(Qb[base + j + 64]);
    Qb[base + j]      = f2bf(x1 * cs - x2 * sn);
    Qb[base + j + 64] = f2bf(x2 * cs + x1 * sn);
  }
  {
    float x1 = bf2f(Kb[base + j]), x2 = bf2f(Kb[base + j + 64]);
    Kb[base + j]      = f2bf(x1 * cs - x2 * sn);
    Kb[base + j + 64] = f2bf(x2 * cs + x1 * sn);
  }
}

// ---------------- flash attention v8 (EXACT revert; measured 133.9us) ----------------
// v9 post-mortem (R7): direct-from-global V fragments (16x 64B segments at
// 8KB stride per instr) thrashed L2 -> HBM-bound 404us, FETCH 26->468MB.
// gll16's CONTIGUOUS 1KB-per-instr staging read is load-bearing. Reverted.
// v8: single-tile blocks (grid 1024 = 16 heads x 64 q-tiles), single K/V
// buffer, LDS 41216 B -> 3 blocks/CU. Block = 4 waves = 2 row-groups x
// 2 key-groups. Head -> XCD pinning: h&7 = b&7.
__global__ __launch_bounds__(256, 3) void attn_k(
    const unsigned short* __restrict__ Qb,   // [NH][T][HD]
    const unsigned short* __restrict__ Kb,   // [NH][T][HD]
    const unsigned short* __restrict__ Vt,   // [NH][HD][T]
    unsigned short* __restrict__ Yb)         // [T][HID]
{
  __shared__ __align__(16) unsigned char smem[41216];
  unsigned short* lK = (unsigned short*)smem;              // [64 keys][128 d] 16 KB
  unsigned short* lV = (unsigned short*)(smem + 16384);    // [128 d][64 keys] 16 KB
  unsigned short (*lP)[32][32] = (unsigned short(*)[32][32])(smem + 32768); // 8 KB
  float* lL = (float*)(smem + 40960);                      // [64]
  float* lO = (float*)smem;                                // [128 d][68] epilogue overlay

  const int tid  = threadIdx.x;
  const int w    = tid >> 6;
  const int rg   = w >> 1;
  const int kg   = w & 1;
  const int lane = tid & 63;
  const int qd   = lane >> 4;
  const int cc   = lane & 15;
  const int cx   = cc & 7;
  const int r8   = lane >> 3, c7 = lane & 7;

  const int b  = blockIdx.x;            // 1024 blocks
  const int h  = b & 15;                // head; h&7 = b&7 -> XCD pinned
  const int tp = 63 - (b >> 4);         // big tiles dispatched first
  const int qrow0 = tp * 64 + rg * 32;
  const int iters = tp + 1;

  // staging source addressing (swizzle on fetch side; slot chunk c holds
  // global chunk c ^ (row&7))
  const int ce  = cc ^ qd;
  const int dlt = (ce & 4) ? -32 : 32;
  const unsigned short* gKbp = Kb + ((size_t)h * T_SEQ + w * 16 + qd) * HD + ce * 8;
  const int cV = c7 ^ r8;
  const unsigned short* gVbp = Vt + ((size_t)h * HD + w * 32 + r8) * T_SEQ + cV * 8;

  // lP store columns (swizzled chunk); read chunk = qd ^ (cc>>2)
  const int pc0 = (((cc >> 3)    ) ^ qd) * 8 + (cc & 7);   // nt=0
  const int pc1 = (((cc >> 3) + 2) ^ qd) * 8 + (cc & 7);   // nt=1

  const f32x4 fzero = {0.f, 0.f, 0.f, 0.f};
  // 50*tanh(s*SCALE/50)*log2(e) ~= s*(B0 + B1*s^2 + B2*s^4)
  const float B0 = 0.09016844006f;
  const float B1 = -4.6962728e-8f;
  const float B2 = 2.9351706e-14f;
  const float CLP = 72.134752f;        // 50 * log2(e)
  short8 onesv;
#pragma unroll
  for (int j = 0; j < 8; ++j) onesv[j] = (short)0x3F80;    // bf16 1.0

  // prologue: stage K(0), V(0)
  {
    unsigned short* dK = lK + w * 2048;
#pragma unroll
    for (int i = 0; i < 4; ++i)
      gll16(gKbp + (size_t)(i * 4) * HD + ((i & 1) ? dlt : 0), dK + i * 512);
    unsigned short* dV = lV + w * 2048;
#pragma unroll
    for (int i = 0; i < 4; ++i)
      gll16(gVbp + (size_t)i * 8 * T_SEQ, dV + i * 512);
  }

  // Q fragments: A-layout, rows qrow0 + mt*16 + cc, d = ks*32 + qd*8
  short8 qf[2][4];
#pragma unroll
  for (int mt = 0; mt < 2; ++mt)
#pragma unroll
    for (int ks = 0; ks < 4; ++ks)
      qf[mt][ks] = *(const short8*)(Qb + ((size_t)h * T_SEQ + qrow0 + mt * 16 + cc) * HD + ks * 32 + qd * 8);

  f32x4 o[2][8];
  f32x4 acc_l[2];
#pragma unroll
  for (int mt = 0; mt < 2; ++mt){
#pragma unroll
    for (int dn = 0; dn < 8; ++dn) o[mt][dn] = fzero;
    acc_l[mt] = fzero;
  }

#pragma unroll 1
  for (int it = 0; it < iters; ++it){
    const int k0 = it * 64;
    VM_WAIT0;          // this wave's K(it)/V(it) landed
    barrier_fence();   // all waves' landed; tiles valid

    // S = Q K^T : wave's keys = k0 + kg*32 + nt*16 + cc (nt=0..1)
    f32x4 S[2][2];
#pragma unroll
    for (int mt = 0; mt < 2; ++mt)
#pragma unroll
      for (int nt = 0; nt < 2; ++nt) S[mt][nt] = fzero;
    __builtin_amdgcn_s_setprio(1);
#pragma unroll
    for (int nt = 0; nt < 2; ++nt){
      short8 kf[4];
#pragma unroll
      for (int ks = 0; ks < 4; ++ks)
        kf[ks] = *(const short8*)(lK + ((kg * 32 + nt * 16 + cc) * 16 + ((ks * 4 + qd) ^ cx)) * 8);
#pragma unroll
      for (int mt = 0; mt < 2; ++mt)
#pragma unroll
        for (int ks = 0; ks < 4; ++ks)
          S[mt][nt] = __builtin_amdgcn_mfma_f32_16x16x32_bf16(qf[mt][ks], kf[ks], S[mt][nt], 0, 0, 0);
    }
    __builtin_amdgcn_s_setprio(0);

    // softcap (poly, log2e folded) + exp2 + P write (mask only last iter)
    const bool domask = (it == iters - 1);
#pragma unroll
    for (int mt = 0; mt < 2; ++mt)
#pragma unroll
      for (int nt = 0; nt < 2; ++nt)
#pragma unroll
        for (int r = 0; r < 4; ++r){
          float s = S[mt][nt][r];
          float w2 = s * s;
          float t = fmaf(w2, B2, B1);
          t = fmaf(w2, t, B0);
          float a = s * t;
          a = __builtin_amdgcn_fmed3f(a, -CLP, CLP);
          float p = __builtin_amdgcn_exp2f(a);
          if (domask){
            int col = k0 + kg * 32 + nt * 16 + cc;
            int row = qrow0 + mt * 16 + qd * 4 + r;
            if (col > row) p = 0.f;
          }
          unsigned u = __builtin_bit_cast(unsigned, p);
          lP[w][mt * 16 + qd * 4 + r][nt ? pc1 : pc0] = (unsigned short)(u >> 16);
        }

    // P fragments (A-layout): row = mt*16+cc, keys qd*8..+7 (same-wave RAW
    // through LDS: compiler inserts the lgkmcnt wait on the data dep)
    short8 pf[2];
#pragma unroll
    for (int mt = 0; mt < 2; ++mt)
      pf[mt] = *(const short8*)(&lP[w][mt * 16 + cc][(qd ^ (cc >> 2)) * 8]);

    // O += P V ; l += P . 1 (ones-MFMA row-sum of stored P)
    __builtin_amdgcn_s_setprio(1);
#pragma unroll
    for (int dn = 0; dn < 8; ++dn){
      short8 vf = *(const short8*)(lV + ((dn * 16 + cc) * 8 + ((kg * 4 + qd) ^ cx)) * 8);
#pragma unroll
      for (int mt = 0; mt < 2; ++mt)
        o[mt][dn] = __builtin_amdgcn_mfma_f32_16x16x32_bf16(pf[mt], vf, o[mt][dn], 0, 0, 0);
    }
#pragma unroll
    for (int mt = 0; mt < 2; ++mt)
      acc_l[mt] = __builtin_amdgcn_mfma_f32_16x16x32_bf16(pf[mt], onesv, acc_l[mt], 0, 0, 0);
    __builtin_amdgcn_s_setprio(0);

    // all lK/lV/lP ds_reads of this wave retired, then barrier: next iter's
    // global_load_lds writes must not land before every wave's reads are done
    LGKM_WAIT0;
    barrier_fence();

    if (it + 1 < iters){
      const unsigned short* gK = gKbp + (size_t)(k0 + 64) * HD;
      unsigned short* dK = lK + w * 2048;
#pragma unroll
      for (int i = 0; i < 4; ++i)
        gll16(gK + (size_t)(i * 4) * HD + ((i & 1) ? dlt : 0), dK + i * 512);
      const unsigned short* gV = gVbp + (k0 + 64);
      unsigned short* dV = lV + w * 2048;
#pragma unroll
      for (int i = 0; i < 4; ++i)
        gll16(gV + (size_t)i * 8 * T_SEQ, dV + i * 512);
    }
  }

  // ---- epilogue: merge kg partials (additive), normalize, store ----
  // acc_l[mt][r] = row-sum for q-row mt*16+qd*4+r (same value in all cc)
  __syncthreads();   // all K/V traffic done before lO overlays the region
  if (kg == 1){
#pragma unroll
    for (int mt = 0; mt < 2; ++mt){
#pragma unroll
      for (int dn = 0; dn < 8; ++dn)
        *(f32x4*)&lO[(dn * 16 + cc) * 68 + rg * 32 + mt * 16 + qd * 4] = o[mt][dn];
      if (cc == 0){
#pragma unroll
        for (int r = 0; r < 4; ++r)
          lL[rg * 32 + mt * 16 + qd * 4 + r] = acc_l[mt][r];
      }
    }
  }
  __syncthreads();
  if (kg == 0){
#pragma unroll
    for (int mt = 0; mt < 2; ++mt){
      float inv[4];
#pragma unroll
      for (int r = 0; r < 4; ++r){
        float lt = acc_l[mt][r] + lL[rg * 32 + mt * 16 + qd * 4 + r];
        inv[r] = __builtin_amdgcn_rcpf(lt);
      }
#pragma unroll
      for (int dn = 0; dn < 8; ++dn){
        f32x4 oo = o[mt][dn] + *(const f32x4*)&lO[(dn * 16 + cc) * 68 + rg * 32 + mt * 16 + qd * 4];
#pragma unroll
        for (int r = 0; r < 4; ++r){
          int row = qrow0 + mt * 16 + qd * 4 + r;
          Yb[(size_t)row * HID + h * HD + dn * 16 + cc] = f2bf(oo[r] * inv[r]);
        }
      }
    }
  }
}

extern "C" void kernel_launch(void* const* d_in, const int* in_sizes, int n_in,
                              void* d_out, int out_size, void* d_ws, size_t ws_size,
                              hipStream_t stream) {
  const float* X  = (const float*)d_in[0];
  const float* Wq = (const float*)d_in[1];
  const float* Wk = (const float*)d_in[2];
  const float* Wv = (const float*)d_in[3];
  const float* Wo = (const float*)d_in[4];
  float* out = (float*)d_out;

  unsigned short* ws = (unsigned short*)d_ws;
  unsigned short* Xb = ws;                                   // [T][HID]        16 MiB
  unsigned short* Wt = ws + (size_t)8  * 1024 * 1024;        // [4*2048][2048]  32 MiB
  unsigned short* Qb = ws + (size_t)24 * 1024 * 1024;        // [NH][T][HD]     16 MiB
  unsigned short* Kb = ws + (size_t)32 * 1024 * 1024;        // [NH][T][HD]     16 MiB
  unsigned short* Vt = ws + (size_t)40 * 1024 * 1024;        // [NH][HD][T]     16 MiB
  unsigned short* Yb = Xb;                                   // reuse X region

  conv_x_k<<<8192, 256, 0, stream>>>(X, Xb);
  conv_wt_k<<<dim3(64, 64, 4), dim3(32, 8), 0, stream>>>(Wq, Wk, Wv, Wo, Wt);
  gemm_bt<0, 6144><<<dim3(48, 32), 256, 0, stream>>>(Xb, Wt, Qb, Kb, Vt, nullptr);
  rope_k<<<dim3(1024, NH), 256, 0, stream>>>(Qb, Kb);
  attn_k<<<dim3(1024), 256, 0, stream>>>(Qb, Kb, Vt, Yb);
  gemm_bt<1, 2048><<<dim3(16, 32), 256, 0, stream>>>(Yb, Wt + (size_t)6144 * 2048,
                                                     nullptr, nullptr, nullptr, out);
}